// Round 1
// baseline (413.110 us; speedup 1.0000x reference)
//
#include <hip/hip_runtime.h>
#include <hip/hip_bf16.h>

// GCN forward: emb-gather -> GCNConv(64->128) -> ReLU -> GCNConv(128->128) -> ReLU
//              -> global_max_pool -> Linear(128->10)
// Fixed sizes: N=100000, E=600000, VOCAB=5000, G=2000, C=10.

__global__ __launch_bounds__(256) void k_deg(const int* __restrict__ dst, int* __restrict__ deg, int E) {
    int e = blockIdx.x * 256 + threadIdx.x;
    if (e < E) atomicAdd(&deg[dst[e]], 1);
}

__global__ __launch_bounds__(256) void k_dinv(const int* __restrict__ deg, float* __restrict__ dinv, int N) {
    int i = blockIdx.x * 256 + threadIdx.x;
    if (i < N) dinv[i] = rsqrtf((float)(deg[i] + 1));  // +1 self-loop
}

// Block-local exclusive scan of deg -> rowstart (partial), block sums -> bsums
__global__ __launch_bounds__(256) void k_scan1(const int* __restrict__ deg, int* __restrict__ exc,
                                               int* __restrict__ bsums, int N) {
    __shared__ int s[256];
    int i = blockIdx.x * 256 + threadIdx.x;
    int v = (i < N) ? deg[i] : 0;
    s[threadIdx.x] = v;
    __syncthreads();
    for (int off = 1; off < 256; off <<= 1) {
        int t = (threadIdx.x >= (unsigned)off) ? s[threadIdx.x - off] : 0;
        __syncthreads();
        s[threadIdx.x] += t;
        __syncthreads();
    }
    if (i < N) exc[i] = s[threadIdx.x] - v;
    if (threadIdx.x == 255) bsums[blockIdx.x] = s[255];
}

// Exclusive scan of block sums (nb <= 512)
__global__ __launch_bounds__(512) void k_scan2(int* __restrict__ bsums, int nb) {
    __shared__ int s[512];
    int i = threadIdx.x;
    int v = (i < nb) ? bsums[i] : 0;
    s[i] = v;
    __syncthreads();
    for (int off = 1; off < 512; off <<= 1) {
        int t = (i >= off) ? s[i - off] : 0;
        __syncthreads();
        s[i] += t;
        __syncthreads();
    }
    if (i < nb) bsums[i] = s[i] - v;
}

__global__ __launch_bounds__(256) void k_scan3(int* __restrict__ rowstart, int* __restrict__ cursor,
                                               const int* __restrict__ bsums, int N, int E) {
    int i = blockIdx.x * 256 + threadIdx.x;
    if (i < N) {
        int r = rowstart[i] + bsums[blockIdx.x];
        rowstart[i] = r;
        cursor[i] = r;
    }
    if (i == 0 && blockIdx.x == 0) rowstart[N] = E;
}

__global__ __launch_bounds__(256) void k_fill(const int* __restrict__ src, const int* __restrict__ dst,
                                              int* __restrict__ cursor, int* __restrict__ cols, int E) {
    int e = blockIdx.x * 256 + threadIdx.x;
    if (e < E) {
        int d = dst[e];
        int pos = atomicAdd(&cursor[d], 1);
        cols[pos] = src[e];
    }
}

// embW1[v][c] = sum_k emb[v][k] * W1[k][c]   (VOCAB x 64) @ (64 x 128)
__global__ __launch_bounds__(256) void k_embW1(const float* __restrict__ emb, const float* __restrict__ W1,
                                               float* __restrict__ out, int VOCAB) {
    int t = blockIdx.x * 256 + threadIdx.x;
    if (t >= VOCAB * 32) return;
    int v = t >> 5, cq = t & 31;
    const float* er = emb + (size_t)v * 64;
    float4 acc = make_float4(0.f, 0.f, 0.f, 0.f);
#pragma unroll 8
    for (int k = 0; k < 64; ++k) {
        float e = er[k];
        float4 w = *(const float4*)&W1[k * 128 + cq * 4];
        acc.x += e * w.x; acc.y += e * w.y; acc.z += e * w.z; acc.w += e * w.w;
    }
    *(float4*)&out[(size_t)v * 128 + cq * 4] = acc;
}

// Layer-1 aggregation: out[i][f] = relu(dinv[i] * (dinv[i]*T[x[i]][f] + sum_j dinv[j]*T[x[j]][f]) + b[f])
__global__ __launch_bounds__(256) void k_agg1(const float* __restrict__ T, const int* __restrict__ x,
                                              const float* __restrict__ dinv, const int* __restrict__ rs,
                                              const int* __restrict__ cols, const float* __restrict__ b,
                                              float* __restrict__ out, int N) {
    int node = blockIdx.x * 2 + (threadIdx.x >> 7);
    int f = threadIdx.x & 127;
    if (node >= N) return;
    float di = dinv[node];
    float acc = di * T[(size_t)x[node] * 128 + f];
    int e0 = rs[node], e1 = rs[node + 1];
    for (int e = e0; e < e1; ++e) {
        int j = cols[e];
        acc += dinv[j] * T[(size_t)x[j] * 128 + f];
    }
    out[(size_t)node * 128 + f] = fmaxf(fmaf(di, acc, b[f]), 0.f);
}

// hlin2 = h1 @ W2   (N x 128) @ (128 x 128), fp32, 64x64 tile, 4x4 per thread
__global__ __launch_bounds__(256) void k_gemm(const float* __restrict__ A, const float* __restrict__ W,
                                              float* __restrict__ B, int N) {
    __shared__ float sA[32][68];  // sA[k][r], padded: 16B-aligned float4 rows, bank-spread
    __shared__ float sW[32][68];  // sW[k][c]
    int tid = threadIdx.x;
    int tx = tid & 15, ty = tid >> 4;
    int row0 = blockIdx.x * 64;
    int col0 = blockIdx.y * 64;
    float acc[4][4] = {};
    for (int kb = 0; kb < 128; kb += 32) {
#pragma unroll
        for (int i = 0; i < 2; ++i) {
            int idx = tid * 2 + i;          // 0..511
            int r = idx >> 3, kq = idx & 7; // A: 64 rows x 8 float4
            float4 v = make_float4(0.f, 0.f, 0.f, 0.f);
            int gr = row0 + r;
            if (gr < N) v = *(const float4*)&A[(size_t)gr * 128 + kb + kq * 4];
            sA[kq * 4 + 0][r] = v.x;
            sA[kq * 4 + 1][r] = v.y;
            sA[kq * 4 + 2][r] = v.z;
            sA[kq * 4 + 3][r] = v.w;
            int kk = idx >> 4, cq = idx & 15;  // W: 32 k x 16 float4
            *(float4*)&sW[kk][cq * 4] = *(const float4*)&W[(size_t)(kb + kk) * 128 + col0 + cq * 4];
        }
        __syncthreads();
#pragma unroll
        for (int k = 0; k < 32; ++k) {
            float4 a = *(const float4*)&sA[k][ty * 4];
            float4 w = *(const float4*)&sW[k][tx * 4];
            float av[4] = {a.x, a.y, a.z, a.w};
            float wv[4] = {w.x, w.y, w.z, w.w};
#pragma unroll
            for (int i = 0; i < 4; ++i)
#pragma unroll
                for (int j = 0; j < 4; ++j) acc[i][j] += av[i] * wv[j];
        }
        __syncthreads();
    }
#pragma unroll
    for (int i = 0; i < 4; ++i) {
        int gr = row0 + ty * 4 + i;
        if (gr < N)
            *(float4*)&B[(size_t)gr * 128 + col0 + tx * 4] =
                make_float4(acc[i][0], acc[i][1], acc[i][2], acc[i][3]);
    }
}

// Layer-2 aggregation fused with global_max_pool:
// z = dinv[i]*(dinv[i]*H[i][f] + sum_j dinv[j]*H[j][f]) + b[f]
// pool[batch[i]][f] = max over i of relu(z)  — via int-bits atomicMax, pool init 0
__global__ __launch_bounds__(256) void k_agg2pool(const float* __restrict__ H, const int* __restrict__ batch,
                                                  const float* __restrict__ dinv, const int* __restrict__ rs,
                                                  const int* __restrict__ cols, const float* __restrict__ b,
                                                  float* __restrict__ pool, int N) {
    int node = blockIdx.x * 2 + (threadIdx.x >> 7);
    int f = threadIdx.x & 127;
    if (node >= N) return;
    float di = dinv[node];
    float acc = di * H[(size_t)node * 128 + f];
    int e0 = rs[node], e1 = rs[node + 1];
    for (int e = e0; e < e1; ++e) {
        int j = cols[e];
        acc += dinv[j] * H[(size_t)j * 128 + f];
    }
    float z = fmaf(di, acc, b[f]);
    // Non-negative target (init 0): int compare == float compare for the max with 0 present.
    atomicMax((int*)&pool[(size_t)batch[node] * 128 + f], __float_as_int(z));
}

// out[g][c] = blin[c] + sum_f pool[g][f] * Wlin[f][c]
__global__ __launch_bounds__(256) void k_final(const float* __restrict__ pool, const float* __restrict__ Wlin,
                                               const float* __restrict__ blin, float* __restrict__ out, int G) {
    int t = blockIdx.x * 256 + threadIdx.x;
    if (t >= G * 10) return;
    int g = t / 10, c = t % 10;
    float acc = blin[c];
    const float* pr = pool + (size_t)g * 128;
#pragma unroll 8
    for (int f = 0; f < 128; ++f) acc = fmaf(pr[f], Wlin[f * 10 + c], acc);
    out[t] = acc;
}

extern "C" void kernel_launch(void* const* d_in, const int* in_sizes, int n_in,
                              void* d_out, int out_size, void* d_ws, size_t ws_size,
                              hipStream_t stream) {
    const int* x = (const int*)d_in[0];
    const int* ei = (const int*)d_in[1];
    const int* batch = (const int*)d_in[2];
    const float* emb = (const float*)d_in[4];
    const float* W1 = (const float*)d_in[5];
    const float* b1 = (const float*)d_in[6];
    const float* W2 = (const float*)d_in[7];
    const float* b2 = (const float*)d_in[8];
    const float* Wlin = (const float*)d_in[9];
    const float* blin = (const float*)d_in[10];
    float* out = (float*)d_out;

    int N = in_sizes[0];
    int E = in_sizes[1] / 2;
    int VOCAB = in_sizes[4] / 64;
    int G = out_size / 10;
    const int* srcp = ei;
    const int* dstp = ei + E;

    char* p = (char*)d_ws;
    auto alloc = [&](size_t bytes) -> char* {
        char* r = p;
        p += (bytes + 255) & ~(size_t)255;
        return r;
    };
    int* deg = (int*)alloc((size_t)N * 4);
    int* cursor = (int*)alloc((size_t)N * 4);
    int* rowstart = (int*)alloc((size_t)(N + 1) * 4);
    int* bsums = (int*)alloc(512 * 4);
    float* dinv = (float*)alloc((size_t)N * 4);
    int* cols = (int*)alloc((size_t)E * 4);
    float* embW1 = (float*)alloc((size_t)VOCAB * 128 * 4);
    float* h1 = (float*)alloc((size_t)N * 128 * 4);
    float* hlin2 = (float*)alloc((size_t)N * 128 * 4);
    float* pool = (float*)alloc((size_t)G * 128 * 4);

    hipMemsetAsync(deg, 0, (size_t)N * 4, stream);
    hipMemsetAsync(pool, 0, (size_t)G * 128 * 4, stream);

    int gE = (E + 255) / 256;
    int gN = (N + 255) / 256;  // 391 <= 512 (scan2 capacity)

    k_deg<<<gE, 256, 0, stream>>>(dstp, deg, E);
    k_dinv<<<gN, 256, 0, stream>>>(deg, dinv, N);
    k_scan1<<<gN, 256, 0, stream>>>(deg, rowstart, bsums, N);
    k_scan2<<<1, 512, 0, stream>>>(bsums, gN);
    k_scan3<<<gN, 256, 0, stream>>>(rowstart, cursor, bsums, N, E);
    k_fill<<<gE, 256, 0, stream>>>(srcp, dstp, cursor, cols, E);
    k_embW1<<<(VOCAB * 32 + 255) / 256, 256, 0, stream>>>(emb, W1, embW1, VOCAB);
    k_agg1<<<(N + 1) / 2, 256, 0, stream>>>(embW1, x, dinv, rowstart, cols, b1, h1, N);
    dim3 gg((N + 63) / 64, 2);
    k_gemm<<<gg, 256, 0, stream>>>(h1, W2, hlin2, N);
    k_agg2pool<<<(N + 1) / 2, 256, 0, stream>>>(hlin2, batch, dinv, rowstart, cols, b2, pool, N);
    k_final<<<(G * 10 + 255) / 256, 256, 0, stream>>>(pool, Wlin, blin, out, G);
}

// Round 2
// 269.417 us; speedup vs baseline: 1.5333x; 1.5333x over previous
//
#include <hip/hip_runtime.h>
#include <hip/hip_bf16.h>
#include <hip/hip_fp16.h>

// GCN forward: emb-gather -> GCNConv(64->128) -> ReLU -> GCNConv(128->128) -> ReLU
//              -> global_max_pool -> Linear(128->10)
// Fixed sizes: N=100000, E=600000, VOCAB=5000, G=2000, C=10.

__global__ __launch_bounds__(256) void k_deg(const int* __restrict__ dst, int* __restrict__ deg, int E) {
    int e = blockIdx.x * 256 + threadIdx.x;
    if (e < E) atomicAdd(&deg[dst[e]], 1);
}

__global__ __launch_bounds__(256) void k_dinv(const int* __restrict__ deg, float* __restrict__ dinv, int N) {
    int i = blockIdx.x * 256 + threadIdx.x;
    if (i < N) dinv[i] = rsqrtf((float)(deg[i] + 1));  // +1 self-loop
}

// Block-local exclusive scan of deg -> rowstart (partial), block sums -> bsums
__global__ __launch_bounds__(256) void k_scan1(const int* __restrict__ deg, int* __restrict__ exc,
                                               int* __restrict__ bsums, int N) {
    __shared__ int s[256];
    int i = blockIdx.x * 256 + threadIdx.x;
    int v = (i < N) ? deg[i] : 0;
    s[threadIdx.x] = v;
    __syncthreads();
    for (int off = 1; off < 256; off <<= 1) {
        int t = (threadIdx.x >= (unsigned)off) ? s[threadIdx.x - off] : 0;
        __syncthreads();
        s[threadIdx.x] += t;
        __syncthreads();
    }
    if (i < N) exc[i] = s[threadIdx.x] - v;
    if (threadIdx.x == 255) bsums[blockIdx.x] = s[255];
}

// Exclusive scan of block sums (nb <= 512)
__global__ __launch_bounds__(512) void k_scan2(int* __restrict__ bsums, int nb) {
    __shared__ int s[512];
    int i = threadIdx.x;
    int v = (i < nb) ? bsums[i] : 0;
    s[i] = v;
    __syncthreads();
    for (int off = 1; off < 512; off <<= 1) {
        int t = (i >= off) ? s[i - off] : 0;
        __syncthreads();
        s[i] += t;
        __syncthreads();
    }
    if (i < nb) bsums[i] = s[i] - v;
}

__global__ __launch_bounds__(256) void k_scan3(int* __restrict__ rowstart, int* __restrict__ cursor,
                                               const int* __restrict__ bsums, int N, int E) {
    int i = blockIdx.x * 256 + threadIdx.x;
    if (i < N) {
        int r = rowstart[i] + bsums[blockIdx.x];
        rowstart[i] = r;
        cursor[i] = r;
    }
    if (i == 0 && blockIdx.x == 0) rowstart[N] = E;
}

__global__ __launch_bounds__(256) void k_fill(const int* __restrict__ src, const int* __restrict__ dst,
                                              int* __restrict__ cursor, int* __restrict__ cols, int E) {
    int e = blockIdx.x * 256 + threadIdx.x;
    if (e < E) {
        int d = dst[e];
        int pos = atomicAdd(&cursor[d], 1);
        cols[pos] = src[e];
    }
}

// embW1[v][c] = sum_k emb[v][k] * W1[k][c]   (VOCAB x 64) @ (64 x 128)
__global__ __launch_bounds__(256) void k_embW1(const float* __restrict__ emb, const float* __restrict__ W1,
                                               float* __restrict__ out, int VOCAB) {
    int t = blockIdx.x * 256 + threadIdx.x;
    if (t >= VOCAB * 32) return;
    int v = t >> 5, cq = t & 31;
    const float* er = emb + (size_t)v * 64;
    float4 acc = make_float4(0.f, 0.f, 0.f, 0.f);
#pragma unroll 8
    for (int k = 0; k < 64; ++k) {
        float e = er[k];
        float4 w = *(const float4*)&W1[k * 128 + cq * 4];
        acc.x += e * w.x; acc.y += e * w.y; acc.z += e * w.z; acc.w += e * w.w;
    }
    *(float4*)&out[(size_t)v * 128 + cq * 4] = acc;
}

// Layer-1 aggregation. One node per wave: lane = feature-pair (float2), wave-uniform edge list.
// h1[i] = relu(di*(di*T[x_i] + sum_j dj*T[x_j]) + b1)
__global__ __launch_bounds__(256) void k_agg1(const float2* __restrict__ T2, const int* __restrict__ x,
                                              const float* __restrict__ dinv, const int* __restrict__ rs,
                                              const int* __restrict__ cols, const float* __restrict__ b1,
                                              float2* __restrict__ out, int N) {
    int f2 = threadIdx.x & 63;   // feature pair index (covers 128 features)
    int ng = threadIdx.x >> 6;   // wave id 0..3 -> node
    int node = blockIdx.x * 4 + ng;
    if (node >= N) return;
    float di = dinv[node];
    float2 t = T2[(size_t)x[node] * 64 + f2];
    float2 acc = make_float2(di * t.x, di * t.y);
    int e0 = rs[node], e1 = rs[node + 1];
    int e = e0;
    for (; e + 1 < e1; e += 2) {
        int j0 = cols[e], j1 = cols[e + 1];
        float d0 = dinv[j0], d1 = dinv[j1];
        float2 a = T2[(size_t)x[j0] * 64 + f2];
        float2 c = T2[(size_t)x[j1] * 64 + f2];
        acc.x += d0 * a.x + d1 * c.x;
        acc.y += d0 * a.y + d1 * c.y;
    }
    if (e < e1) {
        int j = cols[e];
        float dj = dinv[j];
        float2 a = T2[(size_t)x[j] * 64 + f2];
        acc.x += dj * a.x;
        acc.y += dj * a.y;
    }
    float bx = b1[f2 * 2], by = b1[f2 * 2 + 1];
    float2 o;
    o.x = fmaxf(fmaf(di, acc.x, bx), 0.f);
    o.y = fmaxf(fmaf(di, acc.y, by), 0.f);
    out[(size_t)node * 64 + f2] = o;
}

// P = dinv[i] * (h1 @ W2), stored fp16.  (N x 128) @ (128 x 128), 64x64 tile, 4x4/thread.
__global__ __launch_bounds__(256) void k_gemm(const float* __restrict__ A, const float* __restrict__ W,
                                              const float* __restrict__ dinv, __half2* __restrict__ P, int N) {
    __shared__ float sA[32][68];  // sA[k][r]
    __shared__ float sW[32][68];  // sW[k][c]
    int tid = threadIdx.x;
    int tx = tid & 15, ty = tid >> 4;
    int row0 = blockIdx.x * 64;
    int col0 = blockIdx.y * 64;
    float acc[4][4] = {};
    for (int kb = 0; kb < 128; kb += 32) {
#pragma unroll
        for (int i = 0; i < 2; ++i) {
            int idx = tid * 2 + i;          // 0..511
            int r = idx >> 3, kq = idx & 7; // A: 64 rows x 8 float4
            float4 v = make_float4(0.f, 0.f, 0.f, 0.f);
            int gr = row0 + r;
            if (gr < N) v = *(const float4*)&A[(size_t)gr * 128 + kb + kq * 4];
            sA[kq * 4 + 0][r] = v.x;
            sA[kq * 4 + 1][r] = v.y;
            sA[kq * 4 + 2][r] = v.z;
            sA[kq * 4 + 3][r] = v.w;
            int kk = idx >> 4, cq = idx & 15;  // W: 32 k x 16 float4
            *(float4*)&sW[kk][cq * 4] = *(const float4*)&W[(size_t)(kb + kk) * 128 + col0 + cq * 4];
        }
        __syncthreads();
#pragma unroll
        for (int k = 0; k < 32; ++k) {
            float4 a = *(const float4*)&sA[k][ty * 4];
            float4 w = *(const float4*)&sW[k][tx * 4];
            float av[4] = {a.x, a.y, a.z, a.w};
            float wv[4] = {w.x, w.y, w.z, w.w};
#pragma unroll
            for (int i = 0; i < 4; ++i)
#pragma unroll
                for (int j = 0; j < 4; ++j) acc[i][j] += av[i] * wv[j];
        }
        __syncthreads();
    }
#pragma unroll
    for (int i = 0; i < 4; ++i) {
        int gr = row0 + ty * 4 + i;
        if (gr < N) {
            float di = dinv[gr];
            __half2 p0 = __floats2half2_rn(acc[i][0] * di, acc[i][1] * di);
            __half2 p1 = __floats2half2_rn(acc[i][2] * di, acc[i][3] * di);
            size_t base = (size_t)gr * 64 + (col0 >> 1) + tx * 2;
            P[base] = p0;
            P[base + 1] = p1;
        }
    }
}

// Layer-2 aggregation fused with global_max_pool.
// z_i = di*(P_i + sum_j P_j) + b2  (P pre-scaled by dinv), pool = segmax(relu(z)).
// batch sorted -> each thread handles 4 contiguous nodes, register-run max, few atomics.
#define NB2 16
__global__ __launch_bounds__(256) void k_agg2pool(const __half2* __restrict__ P, const int* __restrict__ batch,
                                                  const float* __restrict__ dinv, const int* __restrict__ rs,
                                                  const int* __restrict__ cols, const float* __restrict__ b2,
                                                  float* __restrict__ pool, int N) {
    int f2 = threadIdx.x & 63;   // feature pair
    int ng = threadIdx.x >> 6;   // wave id 0..3
    int nbase = blockIdx.x * NB2 + ng * (NB2 / 4);
    float bx = b2[f2 * 2], by = b2[f2 * 2 + 1];
    float mx = 0.f, my = 0.f;
    int gcur = -1;
#pragma unroll
    for (int it = 0; it < NB2 / 4; ++it) {
        int node = nbase + it;
        if (node >= N) break;
        int g = batch[node];
        if (g != gcur) {
            if (gcur >= 0) {
                if (mx > 0.f) atomicMax((int*)&pool[(size_t)gcur * 128 + f2 * 2], __float_as_int(mx));
                if (my > 0.f) atomicMax((int*)&pool[(size_t)gcur * 128 + f2 * 2 + 1], __float_as_int(my));
            }
            gcur = g;
            mx = 0.f;
            my = 0.f;
        }
        float2 acc = __half22float2(P[(size_t)node * 64 + f2]);  // self term (pre-scaled)
        int e0 = rs[node], e1 = rs[node + 1];
        int e = e0;
        for (; e + 1 < e1; e += 2) {
            int j0 = cols[e], j1 = cols[e + 1];
            float2 a = __half22float2(P[(size_t)j0 * 64 + f2]);
            float2 c = __half22float2(P[(size_t)j1 * 64 + f2]);
            acc.x += a.x + c.x;
            acc.y += a.y + c.y;
        }
        if (e < e1) {
            int j = cols[e];
            float2 a = __half22float2(P[(size_t)j * 64 + f2]);
            acc.x += a.x;
            acc.y += a.y;
        }
        float di = dinv[node];
        float zx = fmaxf(fmaf(di, acc.x, bx), 0.f);
        float zy = fmaxf(fmaf(di, acc.y, by), 0.f);
        mx = fmaxf(mx, zx);
        my = fmaxf(my, zy);
    }
    if (gcur >= 0) {
        if (mx > 0.f) atomicMax((int*)&pool[(size_t)gcur * 128 + f2 * 2], __float_as_int(mx));
        if (my > 0.f) atomicMax((int*)&pool[(size_t)gcur * 128 + f2 * 2 + 1], __float_as_int(my));
    }
}

// out[g][c] = blin[c] + sum_f pool[g][f] * Wlin[f][c]
__global__ __launch_bounds__(256) void k_final(const float* __restrict__ pool, const float* __restrict__ Wlin,
                                               const float* __restrict__ blin, float* __restrict__ out, int G) {
    int t = blockIdx.x * 256 + threadIdx.x;
    if (t >= G * 10) return;
    int g = t / 10, c = t % 10;
    float acc = blin[c];
    const float* pr = pool + (size_t)g * 128;
#pragma unroll 8
    for (int f = 0; f < 128; ++f) acc = fmaf(pr[f], Wlin[f * 10 + c], acc);
    out[t] = acc;
}

extern "C" void kernel_launch(void* const* d_in, const int* in_sizes, int n_in,
                              void* d_out, int out_size, void* d_ws, size_t ws_size,
                              hipStream_t stream) {
    const int* x = (const int*)d_in[0];
    const int* ei = (const int*)d_in[1];
    const int* batch = (const int*)d_in[2];
    const float* emb = (const float*)d_in[4];
    const float* W1 = (const float*)d_in[5];
    const float* b1 = (const float*)d_in[6];
    const float* W2 = (const float*)d_in[7];
    const float* b2 = (const float*)d_in[8];
    const float* Wlin = (const float*)d_in[9];
    const float* blin = (const float*)d_in[10];
    float* out = (float*)d_out;

    int N = in_sizes[0];
    int E = in_sizes[1] / 2;
    int VOCAB = in_sizes[4] / 64;
    int G = out_size / 10;
    const int* srcp = ei;
    const int* dstp = ei + E;

    char* p = (char*)d_ws;
    auto alloc = [&](size_t bytes) -> char* {
        char* r = p;
        p += (bytes + 255) & ~(size_t)255;
        return r;
    };
    int* deg = (int*)alloc((size_t)N * 4);
    int* cursor = (int*)alloc((size_t)N * 4);
    int* rowstart = (int*)alloc((size_t)(N + 1) * 4);
    int* bsums = (int*)alloc(512 * 4);
    float* dinv = (float*)alloc((size_t)N * 4);
    int* cols = (int*)alloc((size_t)E * 4);
    float* embW1 = (float*)alloc((size_t)VOCAB * 128 * 4);
    float* h1 = (float*)alloc((size_t)N * 128 * 4);
    __half2* P = (__half2*)alloc((size_t)N * 128 * 2);
    float* pool = (float*)alloc((size_t)G * 128 * 4);

    hipMemsetAsync(deg, 0, (size_t)N * 4, stream);
    hipMemsetAsync(pool, 0, (size_t)G * 128 * 4, stream);

    int gE = (E + 255) / 256;
    int gN = (N + 255) / 256;  // 391 <= 512 (scan2 capacity)

    k_deg<<<gE, 256, 0, stream>>>(dstp, deg, E);
    k_dinv<<<gN, 256, 0, stream>>>(deg, dinv, N);
    k_scan1<<<gN, 256, 0, stream>>>(deg, rowstart, bsums, N);
    k_scan2<<<1, 512, 0, stream>>>(bsums, gN);
    k_scan3<<<gN, 256, 0, stream>>>(rowstart, cursor, bsums, N, E);
    k_fill<<<gE, 256, 0, stream>>>(srcp, dstp, cursor, cols, E);
    k_embW1<<<(VOCAB * 32 + 255) / 256, 256, 0, stream>>>(emb, W1, embW1, VOCAB);
    k_agg1<<<(N + 3) / 4, 256, 0, stream>>>((const float2*)embW1, x, dinv, rowstart, cols, b1,
                                            (float2*)h1, N);
    dim3 gg((N + 63) / 64, 2);
    k_gemm<<<gg, 256, 0, stream>>>(h1, W2, dinv, P, N);
    k_agg2pool<<<(N + NB2 - 1) / NB2, 256, 0, stream>>>(P, batch, dinv, rowstart, cols, b2, pool, N);
    k_final<<<(G * 10 + 255) / 256, 256, 0, stream>>>(pool, Wlin, blin, out, G);
}

// Round 3
// 225.168 us; speedup vs baseline: 1.8347x; 1.1965x over previous
//
#include <hip/hip_runtime.h>
#include <hip/hip_bf16.h>
#include <hip/hip_fp16.h>

// GCN forward: emb-gather -> GCNConv(64->128) -> ReLU -> GCNConv(128->128) -> ReLU
//              -> global_max_pool -> Linear(128->10)
// N=100000, E=600000, VOCAB=5000, G=2000, C=10.
// fp16 intermediates (table T, h1, P) — error budget ~1e-3 << 3.5e-3 threshold.

typedef _Float16 h4 __attribute__((ext_vector_type(4)));
typedef _Float16 h8 __attribute__((ext_vector_type(8)));
typedef float f32x4 __attribute__((ext_vector_type(4)));

__global__ __launch_bounds__(256) void k_deg(const int* __restrict__ dst, int* __restrict__ deg, int E) {
    int e = blockIdx.x * 256 + threadIdx.x;
    if (e < E) atomicAdd(&deg[dst[e]], 1);
}

__global__ __launch_bounds__(256) void k_dinv(const int* __restrict__ deg, float* __restrict__ dinv, int N) {
    int i = blockIdx.x * 256 + threadIdx.x;
    if (i < N) dinv[i] = rsqrtf((float)(deg[i] + 1));  // +1 self-loop
}

__global__ __launch_bounds__(256) void k_scan1(const int* __restrict__ deg, int* __restrict__ exc,
                                               int* __restrict__ bsums, int N) {
    __shared__ int s[256];
    int i = blockIdx.x * 256 + threadIdx.x;
    int v = (i < N) ? deg[i] : 0;
    s[threadIdx.x] = v;
    __syncthreads();
    for (int off = 1; off < 256; off <<= 1) {
        int t = (threadIdx.x >= (unsigned)off) ? s[threadIdx.x - off] : 0;
        __syncthreads();
        s[threadIdx.x] += t;
        __syncthreads();
    }
    if (i < N) exc[i] = s[threadIdx.x] - v;
    if (threadIdx.x == 255) bsums[blockIdx.x] = s[255];
}

__global__ __launch_bounds__(512) void k_scan2(int* __restrict__ bsums, int nb) {
    __shared__ int s[512];
    int i = threadIdx.x;
    int v = (i < nb) ? bsums[i] : 0;
    s[i] = v;
    __syncthreads();
    for (int off = 1; off < 512; off <<= 1) {
        int t = (i >= off) ? s[i - off] : 0;
        __syncthreads();
        s[i] += t;
        __syncthreads();
    }
    if (i < nb) bsums[i] = s[i] - v;
}

__global__ __launch_bounds__(256) void k_scan3(int* __restrict__ rowstart, int* __restrict__ cursor,
                                               const int* __restrict__ bsums, int N, int E) {
    int i = blockIdx.x * 256 + threadIdx.x;
    if (i < N) {
        int r = rowstart[i] + bsums[blockIdx.x];
        rowstart[i] = r;
        cursor[i] = r;
    }
    if (i == 0 && blockIdx.x == 0) rowstart[N] = E;
}

// CSR fill + per-edge record {x[src], dinv[src]} so agg1 has a 2-level chain only.
__global__ __launch_bounds__(256) void k_fill(const int* __restrict__ src, const int* __restrict__ dst,
                                              const int* __restrict__ x, const float* __restrict__ dinv,
                                              int* __restrict__ cursor, int* __restrict__ cols,
                                              int2* __restrict__ edata, int E) {
    int e = blockIdx.x * 256 + threadIdx.x;
    if (e < E) {
        int d = dst[e];
        int s = src[e];
        int pos = atomicAdd(&cursor[d], 1);
        cols[pos] = s;
        edata[pos] = make_int2(x[s], __float_as_int(dinv[s]));
    }
}

// T[v] = (emb[v] @ W1) as fp16, (VOCAB x 128)
__global__ __launch_bounds__(256) void k_embW1(const float* __restrict__ emb, const float* __restrict__ W1,
                                               h4* __restrict__ T4, int VOCAB) {
    int t = blockIdx.x * 256 + threadIdx.x;
    if (t >= VOCAB * 32) return;
    int v = t >> 5, cq = t & 31;
    const float* er = emb + (size_t)v * 64;
    float4 acc = make_float4(0.f, 0.f, 0.f, 0.f);
#pragma unroll 8
    for (int k = 0; k < 64; ++k) {
        float e = er[k];
        float4 w = *(const float4*)&W1[k * 128 + cq * 4];
        acc.x += e * w.x; acc.y += e * w.y; acc.z += e * w.z; acc.w += e * w.w;
    }
    h4 o;
    o[0] = (_Float16)acc.x; o[1] = (_Float16)acc.y; o[2] = (_Float16)acc.z; o[3] = (_Float16)acc.w;
    T4[(size_t)v * 32 + cq] = o;
}

// W2T[c][k] = (fp16) W2[k][c]  (128x128)
__global__ __launch_bounds__(256) void k_w2t(const float* __restrict__ W2, _Float16* __restrict__ W2T) {
    int t = blockIdx.x * 256 + threadIdx.x;
    if (t >= 128 * 128) return;
    int c = t >> 7, k = t & 127;
    W2T[c * 128 + k] = (_Float16)W2[k * 128 + c];
}

// Layer-1: h1[i] = relu(di*(di*T[x_i] + sum_e dj*T[xj]) + b1), fp16 out.
// Half-wave (32 lanes) per node, lane = 4 features (8B loads), 4-wide gather unroll.
__global__ __launch_bounds__(256) void k_agg1(const h4* __restrict__ T4, const int* __restrict__ x,
                                              const float* __restrict__ dinv, const int* __restrict__ rs,
                                              const int2* __restrict__ edata, const float4* __restrict__ b14,
                                              h4* __restrict__ h1, int N) {
    int f4i = threadIdx.x & 31;
    int node = blockIdx.x * 8 + (threadIdx.x >> 5);
    if (node >= N) return;
    float di = dinv[node];
    h4 ts = T4[(size_t)x[node] * 32 + f4i];
    float a0 = di * (float)ts[0], a1 = di * (float)ts[1], a2 = di * (float)ts[2], a3 = di * (float)ts[3];
    int e = rs[node], e1 = rs[node + 1];
    for (; e + 4 <= e1; e += 4) {
        int2 d0 = edata[e], d1 = edata[e + 1], d2 = edata[e + 2], d3 = edata[e + 3];
        h4 t0 = T4[(size_t)d0.x * 32 + f4i];
        h4 t1 = T4[(size_t)d1.x * 32 + f4i];
        h4 t2 = T4[(size_t)d2.x * 32 + f4i];
        h4 t3 = T4[(size_t)d3.x * 32 + f4i];
        float w0 = __int_as_float(d0.y), w1 = __int_as_float(d1.y);
        float w2 = __int_as_float(d2.y), w3 = __int_as_float(d3.y);
        a0 += w0 * (float)t0[0] + w1 * (float)t1[0] + w2 * (float)t2[0] + w3 * (float)t3[0];
        a1 += w0 * (float)t0[1] + w1 * (float)t1[1] + w2 * (float)t2[1] + w3 * (float)t3[1];
        a2 += w0 * (float)t0[2] + w1 * (float)t1[2] + w2 * (float)t2[2] + w3 * (float)t3[2];
        a3 += w0 * (float)t0[3] + w1 * (float)t1[3] + w2 * (float)t2[3] + w3 * (float)t3[3];
    }
    for (; e < e1; ++e) {
        int2 d0 = edata[e];
        h4 t0 = T4[(size_t)d0.x * 32 + f4i];
        float w0 = __int_as_float(d0.y);
        a0 += w0 * (float)t0[0];
        a1 += w0 * (float)t0[1];
        a2 += w0 * (float)t0[2];
        a3 += w0 * (float)t0[3];
    }
    float4 b = b14[f4i];
    h4 o;
    o[0] = (_Float16)fmaxf(fmaf(di, a0, b.x), 0.f);
    o[1] = (_Float16)fmaxf(fmaf(di, a1, b.y), 0.f);
    o[2] = (_Float16)fmaxf(fmaf(di, a2, b.z), 0.f);
    o[3] = (_Float16)fmaxf(fmaf(di, a3, b.w), 0.f);
    h1[(size_t)node * 32 + f4i] = o;
}

// P = dinv[i] * (h1 @ W2), fp16 out. MFMA 16x16x32_f16, wave = 16 rows x 128 cols,
// operands loaded straight from global (A rows; W2T 32KB L1/L2-resident). No LDS.
__global__ __launch_bounds__(256) void k_gemm(const _Float16* __restrict__ A, const _Float16* __restrict__ W2T,
                                              const float* __restrict__ dinv, _Float16* __restrict__ P, int N) {
    int lane = threadIdx.x & 63;
    int wid = threadIdx.x >> 6;
    int r = lane & 15, kg = lane >> 4;
    int row0 = blockIdx.x * 64 + wid * 16;
    int arow = row0 + r;
    if (arow >= N) arow = N - 1;
    const _Float16* ab = A + (size_t)arow * 128 + kg * 8;
    const _Float16* bb = W2T + (size_t)r * 128 + kg * 8;
    f32x4 acc[8];
#pragma unroll
    for (int ct = 0; ct < 8; ++ct) acc[ct] = (f32x4){0.f, 0.f, 0.f, 0.f};
#pragma unroll
    for (int kc = 0; kc < 4; ++kc) {
        h8 a = *(const h8*)(ab + kc * 32);
#pragma unroll
        for (int ct = 0; ct < 8; ++ct) {
            h8 b = *(const h8*)(bb + kc * 32 + ct * 2048);
            acc[ct] = __builtin_amdgcn_mfma_f32_16x16x32_f16(a, b, acc[ct], 0, 0, 0);
        }
    }
    float dv[4];
#pragma unroll
    for (int i = 0; i < 4; ++i) {
        int gr = row0 + 4 * kg + i;
        dv[i] = (gr < N) ? dinv[gr] : 0.f;
    }
#pragma unroll
    for (int ct = 0; ct < 8; ++ct) {
#pragma unroll
        for (int i = 0; i < 4; ++i) {
            int gr = row0 + 4 * kg + i;
            if (gr < N) P[(size_t)gr * 128 + ct * 16 + r] = (_Float16)(acc[ct][i] * dv[i]);
        }
    }
}

// Layer-2 + global_max_pool. Half-wave per node-run (4 sorted nodes), register run-max,
// atomicMax only at graph boundaries; skip zeros.
__global__ __launch_bounds__(256) void k_agg2pool(const h4* __restrict__ P4, const int* __restrict__ batch,
                                                  const float* __restrict__ dinv, const int* __restrict__ rs,
                                                  const int* __restrict__ cols, const float4* __restrict__ b24,
                                                  float* __restrict__ pool, int N) {
    int f4i = threadIdx.x & 31;
    int nbase = (blockIdx.x * 8 + (threadIdx.x >> 5)) * 4;
    float4 b = b24[f4i];
    float m0 = 0.f, m1 = 0.f, m2 = 0.f, m3 = 0.f;
    int gcur = -1;
#define EMIT()                                                                              \
    {                                                                                       \
        float* pg = pool + (size_t)gcur * 128 + f4i * 4;                                    \
        if (m0 > 0.f) atomicMax((int*)pg, __float_as_int(m0));                              \
        if (m1 > 0.f) atomicMax((int*)(pg + 1), __float_as_int(m1));                        \
        if (m2 > 0.f) atomicMax((int*)(pg + 2), __float_as_int(m2));                        \
        if (m3 > 0.f) atomicMax((int*)(pg + 3), __float_as_int(m3));                        \
    }
    for (int it = 0; it < 4; ++it) {
        int node = nbase + it;
        if (node >= N) break;
        int g = batch[node];
        if (g != gcur) {
            if (gcur >= 0) EMIT();
            gcur = g;
            m0 = m1 = m2 = m3 = 0.f;
        }
        h4 s = P4[(size_t)node * 32 + f4i];
        float a0 = (float)s[0], a1 = (float)s[1], a2 = (float)s[2], a3 = (float)s[3];
        int e = rs[node], e1 = rs[node + 1];
        for (; e + 4 <= e1; e += 4) {
            int j0 = cols[e], j1 = cols[e + 1], j2 = cols[e + 2], j3 = cols[e + 3];
            h4 t0 = P4[(size_t)j0 * 32 + f4i];
            h4 t1 = P4[(size_t)j1 * 32 + f4i];
            h4 t2 = P4[(size_t)j2 * 32 + f4i];
            h4 t3 = P4[(size_t)j3 * 32 + f4i];
            a0 += (float)t0[0] + (float)t1[0] + (float)t2[0] + (float)t3[0];
            a1 += (float)t0[1] + (float)t1[1] + (float)t2[1] + (float)t3[1];
            a2 += (float)t0[2] + (float)t1[2] + (float)t2[2] + (float)t3[2];
            a3 += (float)t0[3] + (float)t1[3] + (float)t2[3] + (float)t3[3];
        }
        for (; e < e1; ++e) {
            h4 t0 = P4[(size_t)cols[e] * 32 + f4i];
            a0 += (float)t0[0];
            a1 += (float)t0[1];
            a2 += (float)t0[2];
            a3 += (float)t0[3];
        }
        float di = dinv[node];
        m0 = fmaxf(m0, fmaxf(fmaf(di, a0, b.x), 0.f));
        m1 = fmaxf(m1, fmaxf(fmaf(di, a1, b.y), 0.f));
        m2 = fmaxf(m2, fmaxf(fmaf(di, a2, b.z), 0.f));
        m3 = fmaxf(m3, fmaxf(fmaf(di, a3, b.w), 0.f));
    }
    if (gcur >= 0) EMIT();
#undef EMIT
}

// out[g][c] = blin[c] + sum_f pool[g][f] * Wlin[f][c]
__global__ __launch_bounds__(256) void k_final(const float* __restrict__ pool, const float* __restrict__ Wlin,
                                               const float* __restrict__ blin, float* __restrict__ out, int G) {
    int t = blockIdx.x * 256 + threadIdx.x;
    if (t >= G * 10) return;
    int g = t / 10, c = t % 10;
    float acc = blin[c];
    const float* pr = pool + (size_t)g * 128;
#pragma unroll 8
    for (int f = 0; f < 128; ++f) acc = fmaf(pr[f], Wlin[f * 10 + c], acc);
    out[t] = acc;
}

extern "C" void kernel_launch(void* const* d_in, const int* in_sizes, int n_in,
                              void* d_out, int out_size, void* d_ws, size_t ws_size,
                              hipStream_t stream) {
    const int* x = (const int*)d_in[0];
    const int* ei = (const int*)d_in[1];
    const int* batch = (const int*)d_in[2];
    const float* emb = (const float*)d_in[4];
    const float* W1 = (const float*)d_in[5];
    const float* b1 = (const float*)d_in[6];
    const float* W2 = (const float*)d_in[7];
    const float* b2 = (const float*)d_in[8];
    const float* Wlin = (const float*)d_in[9];
    const float* blin = (const float*)d_in[10];
    float* out = (float*)d_out;

    int N = in_sizes[0];
    int E = in_sizes[1] / 2;
    int VOCAB = in_sizes[4] / 64;
    int G = out_size / 10;
    const int* srcp = ei;
    const int* dstp = ei + E;

    char* p = (char*)d_ws;
    auto alloc = [&](size_t bytes) -> char* {
        char* r = p;
        p += (bytes + 255) & ~(size_t)255;
        return r;
    };
    int* deg = (int*)alloc((size_t)N * 4);
    int* cursor = (int*)alloc((size_t)N * 4);
    int* rowstart = (int*)alloc((size_t)(N + 1) * 4);
    int* bsums = (int*)alloc(512 * 4);
    float* dinv = (float*)alloc((size_t)N * 4);
    int* cols = (int*)alloc((size_t)E * 4);
    int2* edata = (int2*)alloc((size_t)E * 8);
    h4* T4 = (h4*)alloc((size_t)VOCAB * 128 * 2);
    _Float16* W2T = (_Float16*)alloc(128 * 128 * 2);
    _Float16* h1 = (_Float16*)alloc((size_t)N * 128 * 2);
    _Float16* P = (_Float16*)alloc((size_t)N * 128 * 2);
    float* pool = (float*)alloc((size_t)G * 128 * 4);

    hipMemsetAsync(deg, 0, (size_t)N * 4, stream);
    hipMemsetAsync(pool, 0, (size_t)G * 128 * 4, stream);

    int gE = (E + 255) / 256;
    int gN = (N + 255) / 256;  // 391 <= 512 (scan2 capacity)

    k_deg<<<gE, 256, 0, stream>>>(dstp, deg, E);
    k_dinv<<<gN, 256, 0, stream>>>(deg, dinv, N);
    k_scan1<<<gN, 256, 0, stream>>>(deg, rowstart, bsums, N);
    k_scan2<<<1, 512, 0, stream>>>(bsums, gN);
    k_scan3<<<gN, 256, 0, stream>>>(rowstart, cursor, bsums, N, E);
    k_fill<<<gE, 256, 0, stream>>>(srcp, dstp, x, dinv, cursor, cols, edata, E);
    k_embW1<<<(VOCAB * 32 + 255) / 256, 256, 0, stream>>>(emb, W1, T4, VOCAB);
    k_w2t<<<64, 256, 0, stream>>>(W2, W2T);
    k_agg1<<<(N + 7) / 8, 256, 0, stream>>>(T4, x, dinv, rowstart, edata, (const float4*)b1, (h4*)h1, N);
    k_gemm<<<(N + 63) / 64, 256, 0, stream>>>(h1, W2T, dinv, P, N);
    k_agg2pool<<<(N + 31) / 32, 256, 0, stream>>>((const h4*)P, batch, dinv, rowstart, cols,
                                                  (const float4*)b2, pool, N);
    k_final<<<(G * 10 + 255) / 256, 256, 0, stream>>>(pool, Wlin, blin, out, G);
}